// Round 3
// baseline (136.127 us; speedup 1.0000x reference)
//
#include <hip/hip_runtime.h>
#include <stdint.h>

typedef unsigned short u16;
typedef unsigned int u32;

typedef __bf16 bfx8 __attribute__((ext_vector_type(8)));
typedef float fx4 __attribute__((ext_vector_type(4)));
typedef float fx16 __attribute__((ext_vector_type(16)));
typedef u16 u16x8 __attribute__((ext_vector_type(8)));

#define GAS __attribute__((address_space(1)))
#define LAS __attribute__((address_space(3)))

__device__ __forceinline__ void gload16(const void* g, void* l) {
  __builtin_amdgcn_global_load_lds((GAS void*)g, (LAS void*)l, 16, 0, 0);
}

__device__ __forceinline__ u16 f2bf(float f) {
  union { float f; u32 u; } v; v.f = f;
  u32 r = v.u + 0x7fffu + ((v.u >> 16) & 1u);
  return (u16)(r >> 16);
}
__device__ __forceinline__ float bf2f(u16 u) {
  union { u32 u; float f; } v; v.u = ((u32)u) << 16;
  return v.f;
}

// ---------------- f32 -> bf16 convert ----------------
__global__ __launch_bounds__(256) void k_cvt(const float* __restrict__ src, u16* __restrict__ dst, int n) {
  int i = (blockIdx.x * 256 + threadIdx.x) * 8;
  if (i >= n) return;
  const float4* s = (const float4*)(src + i);
  float4 a = s[0], b = s[1];
  u16x8 o;
  o[0] = f2bf(a.x); o[1] = f2bf(a.y); o[2] = f2bf(a.z); o[3] = f2bf(a.w);
  o[4] = f2bf(b.x); o[5] = f2bf(b.y); o[6] = f2bf(b.z); o[7] = f2bf(b.w);
  *(u16x8*)(dst + i) = o;
}

// ---------------- GEMM C[M,N] = A[M,K] * B[N,K]^T (bf16 in, f32 acc) ----------------
template <int OUTF32>
__global__ __launch_bounds__(256) void k_gemm_bt(const u16* __restrict__ A, const u16* __restrict__ B,
                                                 void* __restrict__ C, int M, int N, int K) {
  __shared__ char sm[32768];
  const int tid = threadIdx.x;
  const int l = tid & 63, w = tid >> 6;
  const int li = l & 15, lg = l >> 4;
  const int nbm = M >> 7;
  const int bm = blockIdx.x % nbm, bn = blockIdx.x / nbm;
  const int wr = w >> 1, wc = w & 1;

  const u16* gsrc[8];
  int ldso[8];
#pragma unroll
  for (int i = 0; i < 8; ++i) {
    int b = i * 4096 + w * 1024 + l * 16;
    int bb = b & 16383;
    int row = bb >> 7;
    int ch = ((bb >> 4) & 7) ^ (row & 7);
    const u16* mat = (i < 4) ? (A + (size_t)(bm * 128 + row) * K)
                             : (B + (size_t)(bn * 128 + row) * K);
    gsrc[i] = mat + ch * 8;
    ldso[i] = i * 4096 + w * 1024;
  }

  fx4 acc[4][4];
#pragma unroll
  for (int ii = 0; ii < 4; ++ii)
#pragma unroll
    for (int jj = 0; jj < 4; ++jj)
#pragma unroll
      for (int r = 0; r < 4; ++r) acc[ii][jj][r] = 0.f;

  for (int k0 = 0; k0 < K; k0 += 64) {
    __syncthreads();
#pragma unroll
    for (int i = 0; i < 8; ++i) gload16(gsrc[i] + k0, sm + ldso[i]);
    __syncthreads();
#pragma unroll
    for (int kk = 0; kk < 2; ++kk) {
      bfx8 af[4], bfr[4];
#pragma unroll
      for (int mf = 0; mf < 4; ++mf) {
        int row = wr * 64 + mf * 16 + li;
        int ch = (kk * 4 + lg) ^ (row & 7);
        af[mf] = *(const bfx8*)(sm + row * 128 + ch * 16);
      }
#pragma unroll
      for (int nf = 0; nf < 4; ++nf) {
        int row = wc * 64 + nf * 16 + li;
        int ch = (kk * 4 + lg) ^ (row & 7);
        bfr[nf] = *(const bfx8*)(sm + 16384 + row * 128 + ch * 16);
      }
#pragma unroll
      for (int mf = 0; mf < 4; ++mf)
#pragma unroll
        for (int nf = 0; nf < 4; ++nf)
          acc[mf][nf] = __builtin_amdgcn_mfma_f32_16x16x32_bf16(af[mf], bfr[nf], acc[mf][nf], 0, 0, 0);
    }
  }
#pragma unroll
  for (int mf = 0; mf < 4; ++mf)
#pragma unroll
    for (int nf = 0; nf < 4; ++nf)
#pragma unroll
      for (int r = 0; r < 4; ++r) {
        int row = bm * 128 + wr * 64 + mf * 16 + lg * 4 + r;
        int col = bn * 128 + wc * 64 + nf * 16 + li;
        if (OUTF32)
          ((float*)C)[(size_t)row * N + col] = acc[mf][nf][r];
        else
          ((u16*)C)[(size_t)row * N + col] = f2bf(acc[mf][nf][r]);
      }
}

// ---------------- RMSNorm + RoPE on q,k (in place) ----------------
__global__ __launch_bounds__(256) void k_normrope(u16* __restrict__ qkv, const float* __restrict__ cs,
                                                  const float* __restrict__ sn) {
  int w = threadIdx.x >> 6, l = threadIdx.x & 63;
  int task = blockIdx.x * 4 + w;
  int t = task >> 3, h = task & 7;
  int j = (2 * l) & 63;
  float2 cc = *(const float2*)(cs + t * 64 + j);
  float2 ssn = *(const float2*)(sn + t * 64 + j);
#pragma unroll
  for (int s = 0; s < 2; ++s) {
    u16* base = qkv + (size_t)t * 3072 + s * 1024 + h * 128;
    u32 u = *(u32*)(base + 2 * l);
    float v0 = bf2f((u16)(u & 0xffff));
    float v1 = bf2f((u16)(u >> 16));
    float sq = v0 * v0 + v1 * v1;
#pragma unroll
    for (int m = 1; m < 64; m <<= 1) sq += __shfl_xor(sq, m);
    float rn = rsqrtf(sq * (1.f / 128.f) + 1e-6f);
    v0 *= rn; v1 *= rn;
    float p0 = __shfl_xor(v0, 32);
    float p1 = __shfl_xor(v1, 32);
    float o0, o1;
    if (l < 32) { o0 = v0 * cc.x + p0 * ssn.x; o1 = v1 * cc.y + p1 * ssn.y; }
    else        { o0 = -p0 * ssn.x + v0 * cc.x; o1 = -p1 * ssn.y + v1 * cc.y; }
    u32 o = (u32)f2bf(o0) | ((u32)f2bf(o1) << 16);
    *(u32*)(base + 2 * l) = o;
  }
}

// ---------------- v = l0*v + l1*ve, transposed store vt[h][d][t] ----------------
__global__ __launch_bounds__(256) void k_mixv(const u16* __restrict__ qkv, const float* __restrict__ ve,
                                              const float* __restrict__ lam, u16* __restrict__ vt) {
  const int h = blockIdx.x & 7, tb = blockIdx.x >> 3;
  const float l0 = lam[0], l1 = lam[1];
  __shared__ u16 V[64][136];
  const int tid = threadIdx.x;
#pragma unroll
  for (int j = 0; j < 8; ++j) {
    int r = (tid >> 5) + j * 8;
    int c = (tid & 31) * 4;
    int t = tb * 64 + r;
    const u16* vp = qkv + (size_t)t * 3072 + 2048 + h * 128 + c;
    u16 b0 = vp[0], b1 = vp[1], b2 = vp[2], b3 = vp[3];
    float4 e = *(const float4*)(ve + (size_t)t * 1024 + h * 128 + c);
    V[r][c + 0] = f2bf(l0 * bf2f(b0) + l1 * e.x);
    V[r][c + 1] = f2bf(l0 * bf2f(b1) + l1 * e.y);
    V[r][c + 2] = f2bf(l0 * bf2f(b2) + l1 * e.z);
    V[r][c + 3] = f2bf(l0 * bf2f(b3) + l1 * e.w);
  }
  __syncthreads();
#pragma unroll
  for (int j = 0; j < 4; ++j) {
    int d = (tid >> 3) + j * 32;
    int t0 = (tid & 7) * 8;
    u16x8 o;
#pragma unroll
    for (int ii = 0; ii < 8; ++ii) o[ii] = V[t0 + ii][d];
    *(u16x8*)(vt + (size_t)h * 262144 + (size_t)d * 2048 + tb * 64 + t0) = o;
  }
}

// ---------------- split-K causal flash attention ----------------
// block = (h, qb of 128 q-rows, seg of <=512 keys); 4 waves x 32 q-rows.
// inner iter = 64 keys, double-buffered LDS shared by 4 waves.
__global__ __launch_bounds__(256) void k_attn2(const u16* __restrict__ qkv, const u16* __restrict__ vt,
                                               float* __restrict__ part, float* __restrict__ ml) {
  __shared__ char sm[65536];  // 2 x (K 16K + V 16K); epilogue: 4 x 16K per-wave
  const int bid = blockIdx.x;
  const int h = bid / 40;
  const int r40 = bid % 40;
  const int g = (r40 < 4) ? 0 : (r40 < 12) ? 1 : (r40 < 24) ? 2 : 3;
  const int Gt = (g == 0) ? 0 : (g == 1) ? 4 : (g == 2) ? 12 : 24;
  const int nseg = g + 1;
  const int idx = r40 - Gt;
  const int qb = g * 4 + idx / nseg;
  const int s = idx % nseg;
  const int q0 = qb * 128;
  const int seg0 = s * 512;
  const int seg_len = min(512, (qb + 1) * 128 - seg0);
  const int nkt = seg_len >> 6;

  const int tid = threadIdx.x;
  const int l = tid & 63, w = tid >> 6;
  const int li = l & 31, hi = l >> 5;
  const int qrow = q0 + w * 32 + li;
  const int wqmax = q0 + w * 32 + 31;
  const int wqmin = q0 + w * 32;

  bfx8 Q[8];
  {
    const u16* qp = qkv + (size_t)qrow * 3072 + h * 128 + hi * 8;
#pragma unroll
    for (int c = 0; c < 8; ++c) Q[c] = *(const bfx8*)(qp + c * 16);
  }

  const u16* kbase = qkv + 1024 + h * 128;
  const u16* vbase = vt + (size_t)h * 262144;

  auto STAGE = [&](int kt, int buf) {
    const int kabs = seg0 + kt * 64;
    char* dst = sm + buf * 32768;
#pragma unroll
    for (int i = 0; i < 4; ++i) {  // K tile [64][128] bf16, swizzled
      int rel = i * 4096 + w * 1024 + l * 16;
      int row = rel >> 8;
      int ch = ((rel >> 4) & 15) ^ (row & 7);
      gload16(kbase + (size_t)(kabs + row) * 3072 + ch * 8, dst + i * 4096 + w * 1024);
    }
#pragma unroll
    for (int i = 0; i < 4; ++i) {  // Vt tile [128][64] bf16, swizzled
      int rel = i * 4096 + w * 1024 + l * 16;
      int d = rel >> 7;
      int ch = ((rel >> 4) & 7) ^ (d & 7);
      gload16(vbase + (size_t)d * 2048 + kabs + ch * 8, dst + 16384 + i * 4096 + w * 1024);
    }
  };

  fx16 Y[4];
#pragma unroll
  for (int d = 0; d < 4; ++d)
#pragma unroll
    for (int r = 0; r < 16; ++r) Y[d][r] = 0.f;
  float m_run = -1e30f, l_run = 0.f;

  STAGE(0, 0);
  __syncthreads();
  int cur = 0;

  for (int kt = 0; kt < nkt; ++kt) {
    if (kt + 1 < nkt) STAGE(kt + 1, cur ^ 1);
    const int k0 = seg0 + kt * 64;
    if (k0 <= wqmax) {
      const char* kb = sm + cur * 32768;
      const char* vb = kb + 16384;
      fx16 S0, S1;
#pragma unroll
      for (int r = 0; r < 16; ++r) { S0[r] = 0.f; S1[r] = 0.f; }
#pragma unroll
      for (int c = 0; c < 8; ++c) {
        int ch = (c * 2 + hi) ^ (li & 7);
        bfx8 kf0 = *(const bfx8*)(kb + li * 256 + ch * 16);
        bfx8 kf1 = *(const bfx8*)(kb + 8192 + li * 256 + ch * 16);
        S0 = __builtin_amdgcn_mfma_f32_32x32x16_bf16(kf0, Q[c], S0, 0, 0, 0);
        S1 = __builtin_amdgcn_mfma_f32_32x32x16_bf16(kf1, Q[c], S1, 0, 0, 0);
      }
      const bool nomask = (k0 + 63 <= wqmin);
      float p0[16], p1[16];
      float mt = -1e30f;
#pragma unroll
      for (int r = 0; r < 16; ++r) {
        int kk = (r & 3) + 8 * (r >> 2) + 4 * hi;
        float sa = (nomask || (k0 + kk <= qrow)) ? S0[r] * 0.12f : -1e30f;
        float sb = (nomask || (k0 + 32 + kk <= qrow)) ? S1[r] * 0.12f : -1e30f;
        p0[r] = sa; p1[r] = sb;
        mt = fmaxf(mt, fmaxf(sa, sb));
      }
      mt = fmaxf(mt, __shfl_xor(mt, 32));
      float mnew = fmaxf(m_run, mt);
      float alpha = __expf(m_run - mnew);
      float ssum = 0.f;
#pragma unroll
      for (int r = 0; r < 16; ++r) {
        float e0 = __expf(p0[r] - mnew);
        float e1 = __expf(p1[r] - mnew);
        p0[r] = e0; p1[r] = e1; ssum += e0 + e1;
      }
      ssum += __shfl_xor(ssum, 32);
      l_run = l_run * alpha + ssum;
      m_run = mnew;
#pragma unroll
      for (int d = 0; d < 4; ++d)
#pragma unroll
        for (int r = 0; r < 16; ++r) Y[d][r] *= alpha;
#pragma unroll
      for (int kbt = 0; kbt < 2; ++kbt) {
        const float* pp = kbt ? p1 : p0;
        u32 pk[8], pks[8];
#pragma unroll
        for (int i = 0; i < 8; ++i) pk[i] = (u32)f2bf(pp[2 * i]) | ((u32)f2bf(pp[2 * i + 1]) << 16);
#pragma unroll
        for (int i = 0; i < 8; ++i) pks[i] = (u32)__shfl_xor((int)pk[i], 32);
        union { u32 u[4]; bfx8 v; } P0, P1;
        if (hi == 0) {
          P0.u[0] = pk[0];  P0.u[1] = pk[1];  P0.u[2] = pks[0]; P0.u[3] = pks[1];
          P1.u[0] = pk[4];  P1.u[1] = pk[5];  P1.u[2] = pks[4]; P1.u[3] = pks[5];
        } else {
          P0.u[0] = pks[2]; P0.u[1] = pks[3]; P0.u[2] = pk[2];  P0.u[3] = pk[3];
          P1.u[0] = pks[6]; P1.u[1] = pks[7]; P1.u[2] = pk[6];  P1.u[3] = pk[7];
        }
#pragma unroll
        for (int db = 0; db < 4; ++db) {
          int dd = db * 32 + li;
          int c0i = (kbt * 4 + hi) ^ (dd & 7);
          int c1i = (kbt * 4 + 2 + hi) ^ (dd & 7);
          bfx8 v0 = *(const bfx8*)(vb + dd * 128 + c0i * 16);
          bfx8 v1 = *(const bfx8*)(vb + dd * 128 + c1i * 16);
          Y[db] = __builtin_amdgcn_mfma_f32_32x32x16_bf16(v0, P0.v, Y[db], 0, 0, 0);
          Y[db] = __builtin_amdgcn_mfma_f32_32x32x16_bf16(v1, P1.v, Y[db], 0, 0, 0);
        }
      }
    }
    __syncthreads();
    cur ^= 1;
  }

  // epilogue: per-wave private 16KB LDS region, XOR-swizzled f32 transpose (no barriers)
  if (hi == 0) {
    ml[(size_t)bid * 256 + (w * 32 + li) * 2 + 0] = m_run;
    ml[(size_t)bid * 256 + (w * 32 + li) * 2 + 1] = l_run;
  }
  float* Yl = (float*)(sm + w * 16384);  // [32][128] f32, col ^ ((row&7)<<2)
#pragma unroll
  for (int db = 0; db < 4; ++db)
#pragma unroll
    for (int r = 0; r < 16; ++r) {
      int d = db * 32 + (r & 3) + 8 * (r >> 2) + 4 * hi;
      Yl[li * 128 + (d ^ ((li & 7) << 2))] = Y[db][r];
    }
  float* pdst = part + (size_t)bid * 16384;
  {
    int rr = l >> 1, hf = (l & 1) * 64;
    int sx = (rr & 7) << 2;
#pragma unroll
    for (int j = 0; j < 16; ++j) {
      float4 v = *(const float4*)(Yl + rr * 128 + ((hf + j * 4) ^ sx));
      *(float4*)(pdst + (w * 32 + rr) * 128 + hf + j * 4) = v;
    }
  }
}

// ---------------- combine partials + gate ----------------
__global__ __launch_bounds__(256) void k_comb(const float* __restrict__ part, const float* __restrict__ ml,
                                              const float* __restrict__ x, const float* __restrict__ gw,
                                              u16* __restrict__ y) {
  const int b = blockIdx.x;
  const int h = b >> 4, qb = b & 15;
  const int g = qb >> 2;
  const int nseg = g + 1;
  const int Gt = (g == 0) ? 0 : (g == 1) ? 4 : (g == 2) ? 12 : 24;
  const int slot0 = h * 40 + Gt + (qb & 3) * nseg;
  const int t = threadIdx.x;
  const int r = t >> 1, hf = (t & 1) * 64;
  const int q = qb * 128 + r;

  float ms[4], ls[4];
  float M = -1e30f;
#pragma unroll
  for (int s = 0; s < 4; ++s) {
    if (s < nseg) {
      ms[s] = ml[(size_t)(slot0 + s) * 256 + r * 2 + 0];
      ls[s] = ml[(size_t)(slot0 + s) * 256 + r * 2 + 1];
      M = fmaxf(M, ms[s]);
    }
  }
  float wt[4];
  float L = 0.f;
#pragma unroll
  for (int s = 0; s < 4; ++s) {
    if (s < nseg) { wt[s] = __expf(ms[s] - M); L += wt[s] * ls[s]; }
  }
  float4 acc[16];
#pragma unroll
  for (int j = 0; j < 16; ++j) { acc[j].x = 0.f; acc[j].y = 0.f; acc[j].z = 0.f; acc[j].w = 0.f; }
#pragma unroll
  for (int s = 0; s < 4; ++s) {
    if (s < nseg) {
      const float4* P = (const float4*)(part + (size_t)(slot0 + s) * 16384 + r * 128 + hf);
      float ws_ = wt[s];
#pragma unroll
      for (int j = 0; j < 16; ++j) {
        float4 v = P[j];
        acc[j].x += ws_ * v.x; acc[j].y += ws_ * v.y; acc[j].z += ws_ * v.z; acc[j].w += ws_ * v.w;
      }
    }
  }
  float dot = 0.f;
#pragma unroll
  for (int i = 0; i < 12; ++i) dot += x[(size_t)q * 1024 + i] * gw[h * 12 + i];
  float gt_ = 1.f / (1.f + __expf(-dot));
  float sc = gt_ / L;
  u16* yp = y + (size_t)q * 1024 + h * 128 + hf;
#pragma unroll
  for (int j = 0; j < 8; ++j) {
    float4 a = acc[2 * j], bb = acc[2 * j + 1];
    u16x8 o;
    o[0] = f2bf(a.x * sc); o[1] = f2bf(a.y * sc); o[2] = f2bf(a.z * sc); o[3] = f2bf(a.w * sc);
    o[4] = f2bf(bb.x * sc); o[5] = f2bf(bb.y * sc); o[6] = f2bf(bb.z * sc); o[7] = f2bf(bb.w * sc);
    *(u16x8*)(yp + j * 8) = o;
  }
}

extern "C" void kernel_launch(void* const* d_in, const int* in_sizes, int n_in,
                              void* d_out, int out_size, void* d_ws, size_t ws_size,
                              hipStream_t stream) {
  const float* x = (const float*)d_in[0];
  const float* qkvo_w = (const float*)d_in[1];
  const float* gate_w = (const float*)d_in[2];
  const float* ve = (const float*)d_in[3];
  const float* lam = (const float*)d_in[4];
  const float* cosp = (const float*)d_in[5];
  const float* sinp = (const float*)d_in[6];
  float* out = (float*)d_out;

  u16* wb  = (u16*)d_ws;                // 4M elems (weights bf16, 8MB)
  u16* xb  = wb + 4u * 1024 * 1024;     // 2M (4MB)
  u16* qkv = xb + 2u * 1024 * 1024;     // 6M (12MB)
  u16* vt  = qkv + 6u * 1024 * 1024;    // 2M (4MB)
  u16* y   = vt + 2u * 1024 * 1024;     // 2M (4MB)
  float* part = (float*)((char*)d_ws + (size_t)32 * 1024 * 1024);  // 320 slots x 64KB = 20MB
  float* ml = part + (size_t)320 * 16384;                          // 320 x 128 x 2 f32

  k_cvt<<<dim3(2048), dim3(256), 0, stream>>>(qkvo_w, wb, 4 * 1024 * 1024);
  k_cvt<<<dim3(1024), dim3(256), 0, stream>>>(x, xb, 2 * 1024 * 1024);
  k_gemm_bt<0><<<dim3(16 * 24), dim3(256), 0, stream>>>(xb, wb, (void*)qkv, 2048, 3072, 1024);
  k_normrope<<<dim3(4096), dim3(256), 0, stream>>>(qkv, cosp, sinp);
  k_mixv<<<dim3(256), dim3(256), 0, stream>>>(qkv, ve, lam, vt);
  k_attn2<<<dim3(320), dim3(256), 0, stream>>>(qkv, vt, part, ml);
  k_comb<<<dim3(128), dim3(256), 0, stream>>>(part, ml, x, gate_w, y);
  k_gemm_bt<1><<<dim3(16 * 8), dim3(256), 0, stream>>>(y, wb + 3u * 1024 * 1024, (void*)out, 2048, 1024, 1024);
}

// Round 6
// 122.331 us; speedup vs baseline: 1.1128x; 1.1128x over previous
//
#include <hip/hip_runtime.h>
#include <stdint.h>

typedef unsigned short u16;
typedef unsigned int u32;

typedef __bf16 bfx8 __attribute__((ext_vector_type(8)));
typedef float fx4 __attribute__((ext_vector_type(4)));
typedef float fx16 __attribute__((ext_vector_type(16)));
typedef u16 u16x8 __attribute__((ext_vector_type(8)));

#define GAS __attribute__((address_space(1)))
#define LAS __attribute__((address_space(3)))

__device__ __forceinline__ void gload16(const void* g, void* l) {
  __builtin_amdgcn_global_load_lds((GAS void*)g, (LAS void*)l, 16, 0, 0);
}

__device__ __forceinline__ u16 f2bf(float f) {
  union { float f; u32 u; } v; v.f = f;
  u32 r = v.u + 0x7fffu + ((v.u >> 16) & 1u);
  return (u16)(r >> 16);
}
__device__ __forceinline__ float bf2f(u16 u) {
  union { u32 u; float f; } v; v.u = ((u32)u) << 16;
  return v.f;
}

// ---------------- f32 -> bf16 convert ----------------
__global__ __launch_bounds__(256) void k_cvt(const float* __restrict__ src, u16* __restrict__ dst, int n) {
  int i = (blockIdx.x * 256 + threadIdx.x) * 8;
  if (i >= n) return;
  const float4* s = (const float4*)(src + i);
  float4 a = s[0], b = s[1];
  u16x8 o;
  o[0] = f2bf(a.x); o[1] = f2bf(a.y); o[2] = f2bf(a.z); o[3] = f2bf(a.w);
  o[4] = f2bf(b.x); o[5] = f2bf(b.y); o[6] = f2bf(b.z); o[7] = f2bf(b.w);
  *(u16x8*)(dst + i) = o;
}

// ---------------- GEMM C[M,N] = A[M,K] * B[N,K]^T (bf16 in, f32 acc) ----------------
template <int OUTF32>
__global__ __launch_bounds__(256) void k_gemm_bt(const u16* __restrict__ A, const u16* __restrict__ B,
                                                 void* __restrict__ C, int M, int N, int K) {
  __shared__ char sm[32768];
  const int tid = threadIdx.x;
  const int l = tid & 63, w = tid >> 6;
  const int li = l & 15, lg = l >> 4;
  const int nbm = M >> 7;
  const int bm = blockIdx.x % nbm, bn = blockIdx.x / nbm;
  const int wr = w >> 1, wc = w & 1;

  const u16* gsrc[8];
  int ldso[8];
#pragma unroll
  for (int i = 0; i < 8; ++i) {
    int b = i * 4096 + w * 1024 + l * 16;
    int bb = b & 16383;
    int row = bb >> 7;
    int ch = ((bb >> 4) & 7) ^ (row & 7);
    const u16* mat = (i < 4) ? (A + (size_t)(bm * 128 + row) * K)
                             : (B + (size_t)(bn * 128 + row) * K);
    gsrc[i] = mat + ch * 8;
    ldso[i] = i * 4096 + w * 1024;
  }

  fx4 acc[4][4];
#pragma unroll
  for (int ii = 0; ii < 4; ++ii)
#pragma unroll
    for (int jj = 0; jj < 4; ++jj)
#pragma unroll
      for (int r = 0; r < 4; ++r) acc[ii][jj][r] = 0.f;

  for (int k0 = 0; k0 < K; k0 += 64) {
    __syncthreads();
#pragma unroll
    for (int i = 0; i < 8; ++i) gload16(gsrc[i] + k0, sm + ldso[i]);
    __syncthreads();
#pragma unroll
    for (int kk = 0; kk < 2; ++kk) {
      bfx8 af[4], bfr[4];
#pragma unroll
      for (int mf = 0; mf < 4; ++mf) {
        int row = wr * 64 + mf * 16 + li;
        int ch = (kk * 4 + lg) ^ (row & 7);
        af[mf] = *(const bfx8*)(sm + row * 128 + ch * 16);
      }
#pragma unroll
      for (int nf = 0; nf < 4; ++nf) {
        int row = wc * 64 + nf * 16 + li;
        int ch = (kk * 4 + lg) ^ (row & 7);
        bfr[nf] = *(const bfx8*)(sm + 16384 + row * 128 + ch * 16);
      }
#pragma unroll
      for (int mf = 0; mf < 4; ++mf)
#pragma unroll
        for (int nf = 0; nf < 4; ++nf)
          acc[mf][nf] = __builtin_amdgcn_mfma_f32_16x16x32_bf16(af[mf], bfr[nf], acc[mf][nf], 0, 0, 0);
    }
  }
#pragma unroll
  for (int mf = 0; mf < 4; ++mf)
#pragma unroll
    for (int nf = 0; nf < 4; ++nf)
#pragma unroll
      for (int r = 0; r < 4; ++r) {
        int row = bm * 128 + wr * 64 + mf * 16 + lg * 4 + r;
        int col = bn * 128 + wc * 64 + nf * 16 + li;
        if (OUTF32)
          ((float*)C)[(size_t)row * N + col] = acc[mf][nf][r];
        else
          ((u16*)C)[(size_t)row * N + col] = f2bf(acc[mf][nf][r]);
      }
}

// ---------------- RMSNorm + RoPE on q,k (in place) ----------------
__global__ __launch_bounds__(256) void k_normrope(u16* __restrict__ qkv, const float* __restrict__ cs,
                                                  const float* __restrict__ sn) {
  int w = threadIdx.x >> 6, l = threadIdx.x & 63;
  int task = blockIdx.x * 4 + w;
  int t = task >> 3, h = task & 7;
  int j = (2 * l) & 63;
  float2 cc = *(const float2*)(cs + t * 64 + j);
  float2 ssn = *(const float2*)(sn + t * 64 + j);
#pragma unroll
  for (int s = 0; s < 2; ++s) {
    u16* base = qkv + (size_t)t * 3072 + s * 1024 + h * 128;
    u32 u = *(u32*)(base + 2 * l);
    float v0 = bf2f((u16)(u & 0xffff));
    float v1 = bf2f((u16)(u >> 16));
    float sq = v0 * v0 + v1 * v1;
#pragma unroll
    for (int m = 1; m < 64; m <<= 1) sq += __shfl_xor(sq, m);
    float rn = rsqrtf(sq * (1.f / 128.f) + 1e-6f);
    v0 *= rn; v1 *= rn;
    float p0 = __shfl_xor(v0, 32);
    float p1 = __shfl_xor(v1, 32);
    float o0, o1;
    if (l < 32) { o0 = v0 * cc.x + p0 * ssn.x; o1 = v1 * cc.y + p1 * ssn.y; }
    else        { o0 = -p0 * ssn.x + v0 * cc.x; o1 = -p1 * ssn.y + v1 * cc.y; }
    u32 o = (u32)f2bf(o0) | ((u32)f2bf(o1) << 16);
    *(u32*)(base + 2 * l) = o;
  }
}

// ---------------- v = l0*v + l1*ve, transposed store vt[h][d][t] ----------------
__global__ __launch_bounds__(256) void k_mixv(const u16* __restrict__ qkv, const float* __restrict__ ve,
                                              const float* __restrict__ lam, u16* __restrict__ vt) {
  const int h = blockIdx.x & 7, tb = blockIdx.x >> 3;
  const float l0 = lam[0], l1 = lam[1];
  __shared__ u16 V[64][136];
  const int tid = threadIdx.x;
#pragma unroll
  for (int j = 0; j < 8; ++j) {
    int r = (tid >> 5) + j * 8;
    int c = (tid & 31) * 4;
    int t = tb * 64 + r;
    const u16* vp = qkv + (size_t)t * 3072 + 2048 + h * 128 + c;
    u16 b0 = vp[0], b1 = vp[1], b2 = vp[2], b3 = vp[3];
    float4 e = *(const float4*)(ve + (size_t)t * 1024 + h * 128 + c);
    V[r][c + 0] = f2bf(l0 * bf2f(b0) + l1 * e.x);
    V[r][c + 1] = f2bf(l0 * bf2f(b1) + l1 * e.y);
    V[r][c + 2] = f2bf(l0 * bf2f(b2) + l1 * e.z);
    V[r][c + 3] = f2bf(l0 * bf2f(b3) + l1 * e.w);
  }
  __syncthreads();
#pragma unroll
  for (int j = 0; j < 4; ++j) {
    int d = (tid >> 3) + j * 32;
    int t0 = (tid & 7) * 8;
    u16x8 o;
#pragma unroll
    for (int ii = 0; ii < 8; ++ii) o[ii] = V[t0 + ii][d];
    *(u16x8*)(vt + (size_t)h * 262144 + (size_t)d * 2048 + tb * 64 + t0) = o;
  }
}

// ---------------- split-K causal flash attention ----------------
// block = (h, qb of 128 q-rows, seg of <=512 keys); 4 waves x 32 q-rows.
// 32-key inner tile (R1-verified math), 2x16KB double-buffered LDS -> 32KB/block
// for 3-4 blocks/CU residency. Plain __syncthreads (proven sync structure).
__global__ __launch_bounds__(256) void k_attn2(const u16* __restrict__ qkv, const u16* __restrict__ vt,
                                               float* __restrict__ part, float* __restrict__ ml) {
  __shared__ char sm[32768];  // 2 x (K 8K + V 8K); epilogue: 4 x 8K per-wave
  const int bid = blockIdx.x;
  const int h = bid / 40;
  const int r40 = bid % 40;
  const int g = (r40 < 4) ? 0 : (r40 < 12) ? 1 : (r40 < 24) ? 2 : 3;
  const int Gt = (g == 0) ? 0 : (g == 1) ? 4 : (g == 2) ? 12 : 24;
  const int nseg = g + 1;
  const int idx = r40 - Gt;
  const int qb = g * 4 + idx / nseg;
  const int s = idx % nseg;
  const int q0 = qb * 128;
  const int seg0 = s * 512;
  const int seg_len = min(512, (qb + 1) * 128 - seg0);
  const int nkt = seg_len >> 5;

  const int tid = threadIdx.x;
  const int l = tid & 63, w = tid >> 6;
  const int li = l & 31, hi = l >> 5;
  const int qrow = q0 + w * 32 + li;
  const int wqmax = q0 + w * 32 + 31;
  const int wqmin = q0 + w * 32;

  bfx8 Q[8];
  {
    const u16* qp = qkv + (size_t)qrow * 3072 + h * 128 + hi * 8;
#pragma unroll
    for (int c = 0; c < 8; ++c) Q[c] = *(const bfx8*)(qp + c * 16);
  }

  const u16* kbase = qkv + 1024 + h * 128;
  const u16* vbase = vt + (size_t)h * 262144;

  auto STAGE = [&](int kt, int buf) {
    const int kabs = seg0 + kt * 32;
    char* dst = sm + buf * 16384;
#pragma unroll
    for (int i = 0; i < 2; ++i) {  // K tile [32][128] bf16, 256B rows, swizzle ch^=(row&7)
      int j = w * 2 + i;
      int row = j * 4 + (l >> 4);
      int ch = (l & 15) ^ (row & 7);
      gload16(kbase + (size_t)(kabs + row) * 3072 + ch * 8, dst + j * 1024);
    }
#pragma unroll
    for (int i = 0; i < 2; ++i) {  // Vt tile [128][32] bf16, 64B rows, swizzle ch^=(d&3)
      int j = w * 2 + i;
      int d = j * 16 + (l >> 2);
      int ch = (l & 3) ^ (d & 3);
      gload16(vbase + (size_t)d * 2048 + kabs + ch * 8, dst + 8192 + j * 1024);
    }
  };

  fx16 Y[4];
#pragma unroll
  for (int d = 0; d < 4; ++d)
#pragma unroll
    for (int r = 0; r < 16; ++r) Y[d][r] = 0.f;
  float m_run = -1e30f, l_run = 0.f;

  STAGE(0, 0);
  __syncthreads();
  int cur = 0;

  for (int kt = 0; kt < nkt; ++kt) {
    if (kt + 1 < nkt) STAGE(kt + 1, cur ^ 1);
    const int k0 = seg0 + kt * 32;
    if (k0 <= wqmax) {
      const char* kb = sm + cur * 16384;
      const char* vb = kb + 8192;
      fx16 S;
#pragma unroll
      for (int r = 0; r < 16; ++r) S[r] = 0.f;
#pragma unroll
      for (int c = 0; c < 8; ++c) {
        int ch = (c * 2 + hi) ^ (li & 7);
        bfx8 kf = *(const bfx8*)(kb + li * 256 + ch * 16);
        S = __builtin_amdgcn_mfma_f32_32x32x16_bf16(kf, Q[c], S, 0, 0, 0);
      }
      const bool nomask = (k0 + 31 <= wqmin);
      float p[16];
      float mt = -1e30f;
#pragma unroll
      for (int r = 0; r < 16; ++r) {
        int kk = (r & 3) + 8 * (r >> 2) + 4 * hi;
        float sv = (nomask || (k0 + kk <= qrow)) ? S[r] * 0.12f : -1e30f;
        p[r] = sv;
        mt = fmaxf(mt, sv);
      }
      mt = fmaxf(mt, __shfl_xor(mt, 32));
      float mnew = fmaxf(m_run, mt);
      float alpha = __expf(m_run - mnew);
      float ssum = 0.f;
#pragma unroll
      for (int r = 0; r < 16; ++r) { float e = __expf(p[r] - mnew); p[r] = e; ssum += e; }
      ssum += __shfl_xor(ssum, 32);
      l_run = l_run * alpha + ssum;
      m_run = mnew;
#pragma unroll
      for (int d = 0; d < 4; ++d)
#pragma unroll
        for (int r = 0; r < 16; ++r) Y[d][r] *= alpha;
      // P -> bf16 B-operand frags (pack pairs, exchange halves via shfl_xor 32)
      u32 pk[8], pks[8];
#pragma unroll
      for (int i = 0; i < 8; ++i) pk[i] = (u32)f2bf(p[2 * i]) | ((u32)f2bf(p[2 * i + 1]) << 16);
#pragma unroll
      for (int i = 0; i < 8; ++i) pks[i] = (u32)__shfl_xor((int)pk[i], 32);
      union { u32 u[4]; bfx8 v; } P0, P1;
      if (hi == 0) {
        P0.u[0] = pk[0];  P0.u[1] = pk[1];  P0.u[2] = pks[0]; P0.u[3] = pks[1];
        P1.u[0] = pk[4];  P1.u[1] = pk[5];  P1.u[2] = pks[4]; P1.u[3] = pks[5];
      } else {
        P0.u[0] = pks[2]; P0.u[1] = pks[3]; P0.u[2] = pk[2];  P0.u[3] = pk[3];
        P1.u[0] = pks[6]; P1.u[1] = pks[7]; P1.u[2] = pk[6];  P1.u[3] = pk[7];
      }
#pragma unroll
      for (int db = 0; db < 4; ++db) {
        int dd = db * 32 + li;
        int c0i = hi ^ (dd & 3);
        int c1i = (2 + hi) ^ (dd & 3);
        bfx8 v0 = *(const bfx8*)(vb + dd * 64 + c0i * 16);
        bfx8 v1 = *(const bfx8*)(vb + dd * 64 + c1i * 16);
        Y[db] = __builtin_amdgcn_mfma_f32_32x32x16_bf16(v0, P0.v, Y[db], 0, 0, 0);
        Y[db] = __builtin_amdgcn_mfma_f32_32x32x16_bf16(v1, P1.v, Y[db], 0, 0, 0);
      }
    }
    __syncthreads();
    cur ^= 1;
  }

  // epilogue: per-wave private 8KB LDS region, two passes over d-halves (wave-private,
  // compiler fences only -- same-wave DS ops are in-order on CDNA).
  if (hi == 0) {
    ml[(size_t)bid * 256 + (w * 32 + li) * 2 + 0] = m_run;
    ml[(size_t)bid * 256 + (w * 32 + li) * 2 + 1] = l_run;
  }
  float* Yl = (float*)(sm + w * 8192);  // [32][64] f32, col ^ ((row&7)<<2)
  float* pdst = part + (size_t)bid * 16384;
#pragma unroll
  for (int P = 0; P < 2; ++P) {
    asm volatile("" ::: "memory");
#pragma unroll
    for (int dh = 0; dh < 2; ++dh) {
      int db = P * 2 + dh;
#pragma unroll
      for (int r = 0; r < 16; ++r) {
        int dloc = dh * 32 + (r & 3) + 8 * (r >> 2) + 4 * hi;
        Yl[li * 64 + (dloc ^ ((li & 7) << 2))] = Y[db][r];
      }
    }
    asm volatile("" ::: "memory");
    int rr = l >> 1, c0 = (l & 1) * 32, sx = (rr & 7) << 2;
#pragma unroll
    for (int j = 0; j < 8; ++j) {
      float4 v = *(const float4*)(Yl + rr * 64 + ((c0 + j * 4) ^ sx));
      *(float4*)(pdst + (w * 32 + rr) * 128 + P * 64 + c0 + j * 4) = v;
    }
  }
}

// ---------------- combine partials + gate ----------------
__global__ __launch_bounds__(256) void k_comb(const float* __restrict__ part, const float* __restrict__ ml,
                                              const float* __restrict__ x, const float* __restrict__ gw,
                                              u16* __restrict__ y) {
  const int b = blockIdx.x;
  const int h = b >> 4, qb = b & 15;
  const int g = qb >> 2;
  const int nseg = g + 1;
  const int Gt = (g == 0) ? 0 : (g == 1) ? 4 : (g == 2) ? 12 : 24;
  const int slot0 = h * 40 + Gt + (qb & 3) * nseg;
  const int t = threadIdx.x;
  const int r = t >> 1, hf = (t & 1) * 64;
  const int q = qb * 128 + r;

  float ms[4], ls[4];
  float M = -1e30f;
#pragma unroll
  for (int s = 0; s < 4; ++s) {
    if (s < nseg) {
      ms[s] = ml[(size_t)(slot0 + s) * 256 + r * 2 + 0];
      ls[s] = ml[(size_t)(slot0 + s) * 256 + r * 2 + 1];
      M = fmaxf(M, ms[s]);
    }
  }
  float wt[4];
  float L = 0.f;
#pragma unroll
  for (int s = 0; s < 4; ++s) {
    if (s < nseg) { wt[s] = __expf(ms[s] - M); L += wt[s] * ls[s]; }
  }
  float4 acc[16];
#pragma unroll
  for (int j = 0; j < 16; ++j) { acc[j].x = 0.f; acc[j].y = 0.f; acc[j].z = 0.f; acc[j].w = 0.f; }
#pragma unroll
  for (int s = 0; s < 4; ++s) {
    if (s < nseg) {
      const float4* P = (const float4*)(part + (size_t)(slot0 + s) * 16384 + r * 128 + hf);
      float ws_ = wt[s];
#pragma unroll
      for (int j = 0; j < 16; ++j) {
        float4 v = P[j];
        acc[j].x += ws_ * v.x; acc[j].y += ws_ * v.y; acc[j].z += ws_ * v.z; acc[j].w += ws_ * v.w;
      }
    }
  }
  float dot = 0.f;
#pragma unroll
  for (int i = 0; i < 12; ++i) dot += x[(size_t)q * 1024 + i] * gw[h * 12 + i];
  float gt_ = 1.f / (1.f + __expf(-dot));
  float sc = gt_ / L;
  u16* yp = y + (size_t)q * 1024 + h * 128 + hf;
#pragma unroll
  for (int j = 0; j < 8; ++j) {
    float4 a = acc[2 * j], bb = acc[2 * j + 1];
    u16x8 o;
    o[0] = f2bf(a.x * sc); o[1] = f2bf(a.y * sc); o[2] = f2bf(a.z * sc); o[3] = f2bf(a.w * sc);
    o[4] = f2bf(bb.x * sc); o[5] = f2bf(bb.y * sc); o[6] = f2bf(bb.z * sc); o[7] = f2bf(bb.w * sc);
    *(u16x8*)(yp + j * 8) = o;
  }
}

extern "C" void kernel_launch(void* const* d_in, const int* in_sizes, int n_in,
                              void* d_out, int out_size, void* d_ws, size_t ws_size,
                              hipStream_t stream) {
  const float* x = (const float*)d_in[0];
  const float* qkvo_w = (const float*)d_in[1];
  const float* gate_w = (const float*)d_in[2];
  const float* ve = (const float*)d_in[3];
  const float* lam = (const float*)d_in[4];
  const float* cosp = (const float*)d_in[5];
  const float* sinp = (const float*)d_in[6];
  float* out = (float*)d_out;

  u16* wb  = (u16*)d_ws;                // 4M elems (weights bf16, 8MB)
  u16* xb  = wb + 4u * 1024 * 1024;     // 2M (4MB)
  u16* qkv = xb + 2u * 1024 * 1024;     // 6M (12MB)
  u16* vt  = qkv + 6u * 1024 * 1024;    // 2M (4MB)
  u16* y   = vt + 2u * 1024 * 1024;     // 2M (4MB)
  float* part = (float*)((char*)d_ws + (size_t)32 * 1024 * 1024);  // 320 slots x 64KB = 20MB
  float* ml = part + (size_t)320 * 16384;                          // 320 x 128 x 2 f32

  k_cvt<<<dim3(2048), dim3(256), 0, stream>>>(qkvo_w, wb, 4 * 1024 * 1024);
  k_cvt<<<dim3(1024), dim3(256), 0, stream>>>(x, xb, 2 * 1024 * 1024);
  k_gemm_bt<0><<<dim3(16 * 24), dim3(256), 0, stream>>>(xb, wb, (void*)qkv, 2048, 3072, 1024);
  k_normrope<<<dim3(4096), dim3(256), 0, stream>>>(qkv, cosp, sinp);
  k_mixv<<<dim3(256), dim3(256), 0, stream>>>(qkv, ve, lam, vt);
  k_attn2<<<dim3(320), dim3(256), 0, stream>>>(qkv, vt, part, ml);
  k_comb<<<dim3(128), dim3(256), 0, stream>>>(part, ml, x, gate_w, y);
  k_gemm_bt<1><<<dim3(16 * 8), dim3(256), 0, stream>>>(y, wb + 3u * 1024 * 1024, (void*)out, 2048, 1024, 1024);
}